// Round 9
// baseline (237.450 us; speedup 1.0000x reference)
//
#include <hip/hip_runtime.h>

typedef short  s16x8 __attribute__((ext_vector_type(8)));   // 8 bf16 bit patterns
typedef float  f32x4 __attribute__((ext_vector_type(4)));
typedef float  f32x2 __attribute__((ext_vector_type(2)));
typedef unsigned int u32;
typedef unsigned int u32x4 __attribute__((ext_vector_type(4)));
typedef unsigned short u16;

#define DEVI static __device__ __forceinline__

constexpr int T_  = 128;
constexpr int F_  = 14;
constexpr int H_  = 64;
constexpr int BPB = 16;   // batch rows per block
constexpr int RD  = 8;    // handoff ring depth (slack 7)

DEVI u16 f2bf(float f) {                     // RNE, one-time weight convert
  u32 u = __builtin_bit_cast(u32, f);
  u += 0x7fffu + ((u >> 16) & 1u);
  return (u16)(u >> 16);
}
DEVI u16 f2bfF(float f) {                    // round-half-up (x / h in-loop path)
  u32 u = __builtin_bit_cast(u32, f);
  return (u16)((u + 0x8000u) >> 16);
}
DEVI u32 pkbf(float a, float b) {            // pack 2 bf16 into one dword
  u32 ua = __builtin_bit_cast(u32, a) + 0x8000u;
  u32 ub = __builtin_bit_cast(u32, b) + 0x8000u;
  return (ua >> 16) | (ub & 0xffff0000u);
}
// B-frag kt from tanh'd acc tiles: elements 0-3 = tile kt, 4-7 = tile kt+2
DEVI s16x8 packfrag(const f32x4& a, const f32x4& b) {
  u32x4 p;
  p[0] = pkbf(a[0], a[1]); p[1] = pkbf(a[2], a[3]);
  p[2] = pkbf(b[0], b[1]); p[3] = pkbf(b[2], b[3]);
  return __builtin_bit_cast(s16x8, p);
}
DEVI float tanhfast(float x) {
  float e = exp2f(x * -2.8853900817779268f);
  float r = __builtin_amdgcn_rcpf(1.0f + e);
  return __builtin_fmaf(2.0f, r, -1.0f);
}
DEVI f32x4 tanh4(const f32x4& v) {
  f32x4 r;
  r[0] = tanhfast(v[0]); r[1] = tanhfast(v[1]);
  r[2] = tanhfast(v[2]); r[3] = tanhfast(v[3]);
  return r;
}
DEVI f32x4 MFMA(s16x8 a, s16x8 b, f32x4 c) {
  return __builtin_amdgcn_mfma_f32_16x16x32_bf16(a, b, c, 0, 0, 0);
}
DEVI s16x8 ldrow8(const float* p) {          // 8 contiguous fp32 -> bf16 A-frag
  const f32x4 a = ((const f32x4*)p)[0];
  const f32x4 b = ((const f32x4*)p)[1];
  s16x8 r;
  r[0] = (short)f2bf(a[0]); r[1] = (short)f2bf(a[1]);
  r[2] = (short)f2bf(a[2]); r[3] = (short)f2bf(a[3]);
  r[4] = (short)f2bf(b[0]); r[5] = (short)f2bf(b[1]);
  r[6] = (short)f2bf(b[2]); r[7] = (short)f2bf(b[3]);
  return r;
}

// 3 waves/block; wave w owns layer w FULLY (round-5/8 proven math + layouts).
// NO __syncthreads in the T-loop: per-lane volatile LDS flags form a bounded
// producer-consumer queue (ring depth RD, consumed-flags for back-pressure).
//  - producer order: volatile ring write -> volatile flag write (same-wave DS
//    ops complete in order; volatile-volatile pins compiler order)
//  - consumer: spin own-lane flag (cached), volatile ring read, then volatile
//    consumed-flag write (after reads, same ordering argument)
// Each wave free-runs its own t-loop: wave0's global x prefetch is never
// drained (no barriers => no forced vmcnt(0)), skew decouples the waves.
// Per-step MFMA trees parallelized: hh-tree (bc + Ah*F, register operands)
// and input-tree (Ai*Fp into zero-C) run concurrently, summed before tanh.
__global__ __launch_bounds__(192, 1) void rnn_ff(
    const float* __restrict__ x,
    const float* __restrict__ Wih0, const float* __restrict__ Whh0,
    const float* __restrict__ bih0, const float* __restrict__ bhh0,
    const float* __restrict__ Wih1, const float* __restrict__ Whh1,
    const float* __restrict__ bih1, const float* __restrict__ bhh1,
    const float* __restrict__ Wih2, const float* __restrict__ Whh2,
    const float* __restrict__ bih2, const float* __restrict__ bhh2,
    const float* __restrict__ fc1w, const float* __restrict__ fc1b,
    const float* __restrict__ fc2w, const float* __restrict__ fc2b,
    float* __restrict__ out)
{
  __shared__ __align__(16) u32x4 ring[2][RD][2][64]; // [layer][slot][frag][lane] 32 KiB
  __shared__ int   pf[2][64];                        // produced-t flag, per lane
  __shared__ int   cf[2][64];                        // consumed-t flag, per lane
  __shared__ __align__(16) float h2l[BPB][68];       // fc-head unpermute

  const int tid  = threadIdx.x;
  const int w    = tid >> 6;        // wave id = layer id
  const int lane = tid & 63;
  const int g    = lane >> 4;
  const int m    = lane & 15;
  const int b0   = blockIdx.x * BPB;

  // ---- init flags to -1 ----
  for (int i = tid; i < 2 * 64; i += 192) {
    ((int*)pf)[i] = -1;
    ((int*)cf)[i] = -1;
  }

  // ---- per-wave (per-layer) weights, all register-resident (round-8 exact) ----
  s16x8 Ax[4], Ai[4][2], Ah[4][2];
  f32x4 bc[4];
  {
    const float* Wi = Wih1; const float* Wh = Whh0;
    const float* bi = bih0; const float* bh = bhh0;
    if (w == 1)      { Wi = Wih1; Wh = Whh1; bi = bih1; bh = bhh1; }
    else if (w == 2) { Wi = Wih2; Wh = Whh2; bi = bih2; bh = bhh2; }
    #pragma unroll
    for (int n = 0; n < 4; n++) {
      const int Lr = 32 * (n & 1) + 8 * (m >> 2) + 4 * (n >> 1) + (m & 3);
      if (w == 0) {                      // input side 64x14, zero-pad K to 32
        s16x8 r;
        #pragma unroll
        for (int j2 = 0; j2 < 8; j2++) {
          const int kk = 8 * g + j2;
          r[j2] = (kk < F_) ? (short)f2bf(Wih0[Lr * F_ + kk]) : (short)0;
        }
        Ax[n] = r;
        Ai[n][0] = r; Ai[n][1] = r;      // dead in wave0
      } else {
        #pragma unroll
        for (int kt = 0; kt < 2; kt++)
          Ai[n][kt] = ldrow8(Wi + Lr * H_ + 32 * kt + 8 * g);
        Ax[n] = Ai[n][0];                // dead in waves 1/2
      }
      #pragma unroll
      for (int kt = 0; kt < 2; kt++)
        Ah[n][kt] = ldrow8(Wh + Lr * H_ + 32 * kt + 8 * g);
      const int Lb = 32 * (n & 1) + 8 * g + 4 * (n >> 1);
      bc[n] = *(const f32x4*)(bi + Lb) + *(const f32x4*)(bh + Lb);
    }
  }

  // ---- hh-state frags (own layer), zero init ----
  s16x8 F[2];
  {
    s16x8 z;
    #pragma unroll
    for (int i = 0; i < 8; i++) z[i] = 0;
    F[0] = z; F[1] = z;
  }
  f32x4 z4; z4[0] = 0.f; z4[1] = 0.f; z4[2] = 0.f; z4[3] = 0.f;
  f32x4 h2v[4];
  #pragma unroll
  for (int n = 0; n < 4; n++) h2v[n] = z4;

  // ---- wave-0 x pipeline (round-4/8 proven float2 loads, distance 3) ----
  const float* xrow = x + (size_t)(b0 + m) * T_ * F_;
  auto ldraw = [&](int t, f32x4& ra, f32x4& rb) {
    const float* p = xrow + t * F_;
    if (g == 0) {
      f32x2 p0 = *(const f32x2*)(p),     p1 = *(const f32x2*)(p + 2);
      f32x2 p2 = *(const f32x2*)(p + 4), p3 = *(const f32x2*)(p + 6);
      ra[0] = p0[0]; ra[1] = p0[1]; ra[2] = p1[0]; ra[3] = p1[1];
      rb[0] = p2[0]; rb[1] = p2[1]; rb[2] = p3[0]; rb[3] = p3[1];
    } else if (g == 1) {
      f32x2 p4 = *(const f32x2*)(p + 8), p5 = *(const f32x2*)(p + 10);
      f32x2 p6 = *(const f32x2*)(p + 12);
      ra[0] = p4[0]; ra[1] = p4[1]; ra[2] = p5[0]; ra[3] = p5[1];
      rb[0] = p6[0]; rb[1] = p6[1]; rb[2] = 0.f;   rb[3] = 0.f;
    } else {
      ra = z4; rb = z4;
    }
  };
  auto cvtraw = [&](const f32x4& ra, const f32x4& rb) -> s16x8 {
    s16x8 r;
    r[0] = (short)f2bfF(ra[0]); r[1] = (short)f2bfF(ra[1]);
    r[2] = (short)f2bfF(ra[2]); r[3] = (short)f2bfF(ra[3]);
    r[4] = (short)f2bfF(rb[0]); r[5] = (short)f2bfF(rb[1]);
    r[6] = (short)f2bfF(rb[2]); r[7] = (short)f2bfF(rb[3]);
    return r;
  };

  __syncthreads();   // flags visible; loop itself is barrier-free

  if (w == 0) {
    // ================= wave 0: layer 0, x from global =================
    s16x8 bx;
    f32x4 Ba0, Ba1, Ca0, Ca1, Da0, Da1;
    { f32x4 t0, t1; ldraw(0, t0, t1); bx = cvtraw(t0, t1); }
    ldraw(1, Ba0, Ba1);
    ldraw(2, Ca0, Ca1);
    volatile int* cfl = &cf[0][lane];
    int ck = -1;
    #pragma unroll 1
    for (int t = 0; t < T_; t++) {
      { int tp = t + 3; if (tp > T_ - 1) tp = T_ - 1; ldraw(tp, Da0, Da1); }
      if (ck < t - RD) { int k = *cfl; while (k < t - RD) k = *cfl; ck = k; }
      f32x4 p[4], q[4], hv[4];
      #pragma unroll
      for (int n = 0; n < 4; n++) {
        p[n] = MFMA(Ah[n][0], F[0], bc[n]);
        q[n] = MFMA(Ax[n], bx, z4);
      }
      #pragma unroll
      for (int n = 0; n < 4; n++) p[n] = MFMA(Ah[n][1], F[1], p[n]);
      #pragma unroll
      for (int n = 0; n < 4; n++) hv[n] = tanh4(p[n] + q[n]);
      F[0] = packfrag(hv[0], hv[2]);
      F[1] = packfrag(hv[1], hv[3]);
      *(volatile u32x4*)&ring[0][t & (RD - 1)][0][lane] = __builtin_bit_cast(u32x4, F[0]);
      *(volatile u32x4*)&ring[0][t & (RD - 1)][1][lane] = __builtin_bit_cast(u32x4, F[1]);
      *(volatile int*)&pf[0][lane] = t;      // same-wave DS in order => data visible
      bx = cvtraw(Ba0, Ba1);
      Ba0 = Ca0; Ba1 = Ca1; Ca0 = Da0; Ca1 = Da1;
    }
  } else if (w == 1) {
    // ================= wave 1: layer 1 =================
    volatile int* pfl = &pf[0][lane];
    volatile int* cfl = &cf[1][lane];
    int pk = -1, ck = -1;
    #pragma unroll 1
    for (int t = 0; t < T_; t++) {
      if (pk < t) { int k = *pfl; while (k < t) k = *pfl; pk = k; }
      s16x8 Fp0 = __builtin_bit_cast(s16x8, *(volatile u32x4*)&ring[0][t & (RD - 1)][0][lane]);
      s16x8 Fp1 = __builtin_bit_cast(s16x8, *(volatile u32x4*)&ring[0][t & (RD - 1)][1][lane]);
      *(volatile int*)&cf[0][lane] = t;      // reads performed (in-order DS)
      if (ck < t - RD) { int k = *cfl; while (k < t - RD) k = *cfl; ck = k; }
      f32x4 p[4], q[4], hv[4];
      #pragma unroll
      for (int n = 0; n < 4; n++) {
        p[n] = MFMA(Ah[n][0], F[0], bc[n]);
        q[n] = MFMA(Ai[n][0], Fp0, z4);
      }
      #pragma unroll
      for (int n = 0; n < 4; n++) {
        p[n] = MFMA(Ah[n][1], F[1], p[n]);
        q[n] = MFMA(Ai[n][1], Fp1, q[n]);
      }
      #pragma unroll
      for (int n = 0; n < 4; n++) hv[n] = tanh4(p[n] + q[n]);
      F[0] = packfrag(hv[0], hv[2]);
      F[1] = packfrag(hv[1], hv[3]);
      *(volatile u32x4*)&ring[1][t & (RD - 1)][0][lane] = __builtin_bit_cast(u32x4, F[0]);
      *(volatile u32x4*)&ring[1][t & (RD - 1)][1][lane] = __builtin_bit_cast(u32x4, F[1]);
      *(volatile int*)&pf[1][lane] = t;
    }
  } else {
    // ================= wave 2: layer 2 =================
    volatile int* pfl = &pf[1][lane];
    int pk = -1;
    #pragma unroll 1
    for (int t = 0; t < T_; t++) {
      if (pk < t) { int k = *pfl; while (k < t) k = *pfl; pk = k; }
      s16x8 Fp0 = __builtin_bit_cast(s16x8, *(volatile u32x4*)&ring[1][t & (RD - 1)][0][lane]);
      s16x8 Fp1 = __builtin_bit_cast(s16x8, *(volatile u32x4*)&ring[1][t & (RD - 1)][1][lane]);
      *(volatile int*)&cf[1][lane] = t;
      f32x4 p[4], q[4], hv[4];
      #pragma unroll
      for (int n = 0; n < 4; n++) {
        p[n] = MFMA(Ah[n][0], F[0], bc[n]);
        q[n] = MFMA(Ai[n][0], Fp0, z4);
      }
      #pragma unroll
      for (int n = 0; n < 4; n++) {
        p[n] = MFMA(Ah[n][1], F[1], p[n]);
        q[n] = MFMA(Ai[n][1], Fp1, q[n]);
      }
      #pragma unroll
      for (int n = 0; n < 4; n++) hv[n] = tanh4(p[n] + q[n]);
      F[0] = packfrag(hv[0], hv[2]);
      F[1] = packfrag(hv[1], hv[3]);
      if (t == T_ - 1) {
        #pragma unroll
        for (int n = 0; n < 4; n++) h2v[n] = hv[n];   // fp32 h2 for head
      }
    }
  }

  // ---- FC head: wave 2 un-permutes fp32 h2; wave 0 computes (round-8 exact) ----
  if (w == 2) {
    #pragma unroll
    for (int n = 0; n < 4; n++) {
      const int Lb = 32 * (n & 1) + 8 * g + 4 * (n >> 1);
      *(f32x4*)&h2l[m][Lb] = h2v[n];
    }
  }
  __syncthreads();

  if (w == 0) {
    float hr[64];
    #pragma unroll
    for (int q = 0; q < 16; q++) {
      f32x4 v = *(const f32x4*)&h2l[m][4 * q];
      hr[4 * q + 0] = v[0]; hr[4 * q + 1] = v[1];
      hr[4 * q + 2] = v[2]; hr[4 * q + 3] = v[3];
    }
    float acc2 = 0.f;
    #pragma unroll
    for (int jj = 0; jj < 8; jj++) {
      const int jf = 8 * g + jj;
      float s = fc1b[jf];
      const f32x4* wp = (const f32x4*)(fc1w + jf * H_);
      #pragma unroll
      for (int kq = 0; kq < 16; kq++) {
        f32x4 wv = wp[kq];
        s += hr[4 * kq + 0] * wv[0] + hr[4 * kq + 1] * wv[1]
           + hr[4 * kq + 2] * wv[2] + hr[4 * kq + 3] * wv[3];
      }
      s = fmaxf(s, 0.f);
      acc2 += s * fc2w[jf];
    }
    acc2 += __shfl_xor(acc2, 16, 64);
    acc2 += __shfl_xor(acc2, 32, 64);
    if (lane < 16) out[b0 + m] = acc2 + fc2b[0];
  }
}

extern "C" void kernel_launch(void* const* d_in, const int* in_sizes, int n_in,
                              void* d_out, int out_size, void* d_ws, size_t ws_size,
                              hipStream_t stream) {
  const float* x    = (const float*)d_in[0];
  const float* Wih0 = (const float*)d_in[1];
  const float* Whh0 = (const float*)d_in[2];
  const float* bih0 = (const float*)d_in[3];
  const float* bhh0 = (const float*)d_in[4];
  const float* Wih1 = (const float*)d_in[5];
  const float* Whh1 = (const float*)d_in[6];
  const float* bih1 = (const float*)d_in[7];
  const float* bhh1 = (const float*)d_in[8];
  const float* Wih2 = (const float*)d_in[9];
  const float* Whh2 = (const float*)d_in[10];
  const float* bih2 = (const float*)d_in[11];
  const float* bhh2 = (const float*)d_in[12];
  const float* fc1w = (const float*)d_in[13];
  const float* fc1b = (const float*)d_in[14];
  const float* fc2w = (const float*)d_in[15];
  const float* fc2b = (const float*)d_in[16];

  rnn_ff<<<dim3(4096 / BPB), dim3(192), 0, stream>>>(
      x, Wih0, Whh0, bih0, bhh0, Wih1, Whh1, bih1, bhh1,
      Wih2, Whh2, bih2, bhh2, fc1w, fc1b, fc2w, fc2b, (float*)d_out);
}